// Round 2
// baseline (8725.317 us; speedup 1.0000x reference)
//
#include <hip/hip_runtime.h>
#include <math.h>

// BS=8, ROI=512, D=1024, G=16, DH=64, GEO=64, N_total=4096
// ALL I/O is float32 (per reference setup_inputs dtypes).

// ---------------------------------------------------------------- geometry
__global__ __launch_bounds__(256) void geom_kernel(
    const float* __restrict__ boxes,
    float* __restrict__ gcx, float* __restrict__ gcy,
    float* __restrict__ gw,  float* __restrict__ glw, float* __restrict__ glh)
{
    const int i = blockIdx.x * 256 + threadIdx.x;
    if (i >= 4096) return;
    const float x1 = boxes[i * 4 + 0];
    const float y1 = boxes[i * 4 + 1];
    const float x2 = boxes[i * 4 + 2];
    const float y2 = boxes[i * 4 + 3];
    const float w = x2 - x1, h = y2 - y1;
    gcx[i] = 0.5f * (x1 + x2);
    gcy[i] = 0.5f * (y1 + y2);
    gw[i]  = w;
    glw[i] = logf(w);
    glh[i] = logf(h);
}

// ------------------------------------------------- generic NT GEMM (fp32)
// C[m,n] = sum_k A[m,k]*B[n,k] (+ bias[n]); A:[M,K], B:[N,K] row-major f32.
// batched=1: blockIdx.z = b*16+g, A += b*512*1024, B += g*64*1024, C += z*512*64
__global__ __launch_bounds__(256) void gemm_nt(
    const float* __restrict__ A, const float* __restrict__ B,
    const float* __restrict__ bias, float* __restrict__ C,
    int M, int N, int K, int batched)
{
    if (batched) {
        const int bz = blockIdx.z;
        A += (size_t)(bz >> 4) * 512 * 1024;
        B += (size_t)(bz & 15) * 64 * 1024;
        C += (size_t)bz * 512 * 64;
    }
    __shared__ float As[16][64];
    __shared__ float Bs[16][64];
    const int tid = threadIdx.x;
    const int m0 = blockIdx.y << 6;
    const int n0 = blockIdx.x << 6;
    const int tx = tid & 15, ty = tid >> 4;
    const int lr = tid >> 2;          // 0..63 row of tile
    const int lk = (tid & 3) << 2;    // 0,4,8,12 k-offset
    float acc[4][4] = {{0.f}};

    for (int k0 = 0; k0 < K; k0 += 16) {
        const float4 a4 = *reinterpret_cast<const float4*>(A + (size_t)(m0 + lr) * K + k0 + lk);
        const float4 b4 = *reinterpret_cast<const float4*>(B + (size_t)(n0 + lr) * K + k0 + lk);
        As[lk + 0][lr] = a4.x;
        As[lk + 1][lr] = a4.y;
        As[lk + 2][lr] = a4.z;
        As[lk + 3][lr] = a4.w;
        Bs[lk + 0][lr] = b4.x;
        Bs[lk + 1][lr] = b4.y;
        Bs[lk + 2][lr] = b4.z;
        Bs[lk + 3][lr] = b4.w;
        __syncthreads();
        #pragma unroll
        for (int kk = 0; kk < 16; ++kk) {
            float a[4], b[4];
            #pragma unroll
            for (int i = 0; i < 4; ++i) a[i] = As[kk][(ty << 2) + i];
            #pragma unroll
            for (int j = 0; j < 4; ++j) b[j] = Bs[kk][(tx << 2) + j];
            #pragma unroll
            for (int i = 0; i < 4; ++i)
                #pragma unroll
                for (int j = 0; j < 4; ++j) acc[i][j] = fmaf(a[i], b[j], acc[i][j]);
        }
        __syncthreads();
    }
    #pragma unroll
    for (int i = 0; i < 4; ++i) {
        const int row = m0 + (ty << 2) + i;
        #pragma unroll
        for (int j = 0; j < 4; ++j) {
            const int col = n0 + (tx << 2) + j;
            float v = acc[i][j];
            if (bias) v += bias[col];
            C[(size_t)row * N + col] = v;
        }
    }
}

// ------------------------------------------------------- fused attention
// one block per (b, i): geo MLP + logits + softmax + PV + grouped bias + relu
__global__ __launch_bounds__(256) void attn_kernel(
    const float* __restrict__ gcx, const float* __restrict__ gcy,
    const float* __restrict__ gw,  const float* __restrict__ glw,
    const float* __restrict__ glh,
    const float* __restrict__ q, const float* __restrict__ k,
    const float* __restrict__ y,
    const float* __restrict__ W_geo, const float* __restrict__ b_geo,
    const float* __restrict__ W_bgc, const float* __restrict__ b_bgc,
    const float* __restrict__ b_gc,
    float* __restrict__ out)
{
    __shared__ float qs[1024];
    __shared__ float wgt[16][512];
    __shared__ float sWg[256];   // W_geo [64][4]
    __shared__ float sbg[64];
    __shared__ float sWb[1024];  // W_bgc [16][64]
    __shared__ float sbb[16];

    const int tid = threadIdx.x;
    const int bid = blockIdx.x;       // b*512 + i
    const int bb = bid >> 9;

    sWg[tid] = W_geo[tid];
    if (tid < 64) sbg[tid] = b_geo[tid];
    if (tid < 16) sbb[tid] = b_bgc[tid];
    for (int l = tid; l < 1024; l += 256) {
        sWb[l] = W_bgc[l];
        qs[l] = q[(size_t)bid * 1024 + l];
    }
    __syncthreads();

    // ---- phase A: geometric encoding -> tanh MLP -> group conv -> log
    const float cxi = gcx[bid], cyi = gcy[bid];
    const float rwi = 1.0f / gw[bid];
    const float lwi = glw[bid], lhi = glh[bid];

    for (int j = tid; j < 512; j += 256) {
        const int jg = (bb << 9) + j;
        const float e0 = logf(fmaxf(fabsf((cxi - gcx[jg]) * rwi), 1e-3f));
        const float e1 = logf(fmaxf(fabsf((cyi - gcy[jg]) * rwi), 1e-3f));
        const float e2 = lwi - glw[jg];
        const float e3 = lhi - glh[jg];
        float acc[16];
        #pragma unroll
        for (int g = 0; g < 16; ++g) acc[g] = 0.f;
        #pragma unroll 8
        for (int d = 0; d < 64; ++d) {
            float hv = fmaf(e0, sWg[d * 4 + 0], fmaf(e1, sWg[d * 4 + 1],
                       fmaf(e2, sWg[d * 4 + 2], fmaf(e3, sWg[d * 4 + 3], sbg[d]))));
            hv = tanhf(hv);
            #pragma unroll
            for (int g = 0; g < 16; ++g) acc[g] = fmaf(sWb[g * 64 + d], hv, acc[g]);
        }
        #pragma unroll
        for (int g = 0; g < 16; ++g) {
            const float v = fmaxf(acc[g] + sbb[g], 0.f);   // relu
            wgt[g][j] = logf(fmaxf(v, 1e-6f));
        }
    }
    __syncthreads();

    // ---- phase B: add q.k logits (wave per j, lane = dh)
    const int lane = tid & 63, wid = tid >> 6;
    for (int j = wid; j < 512; j += 4) {
        const float* kp = k + (size_t)((bb << 9) + j) * 1024 + lane;
        #pragma unroll
        for (int g = 0; g < 16; ++g) {
            float p = qs[g * 64 + lane] * kp[g * 64];
            #pragma unroll
            for (int off = 32; off > 0; off >>= 1) p += __shfl_xor(p, off);
            if (lane == 0) wgt[g][j] += p * 0.125f;   // 1/sqrt(64)
        }
    }
    __syncthreads();

    // ---- phase C: softmax per group over j (wave wid handles 4 groups)
    for (int gi = 0; gi < 4; ++gi) {
        const int g = wid * 4 + gi;
        float vals[8], m = -3.0e38f;
        #pragma unroll
        for (int r = 0; r < 8; ++r) {
            vals[r] = wgt[g][(r << 6) + lane];
            m = fmaxf(m, vals[r]);
        }
        #pragma unroll
        for (int off = 32; off > 0; off >>= 1) m = fmaxf(m, __shfl_xor(m, off));
        float s = 0.f;
        #pragma unroll
        for (int r = 0; r < 8; ++r) { vals[r] = expf(vals[r] - m); s += vals[r]; }
        #pragma unroll
        for (int off = 32; off > 0; off >>= 1) s += __shfl_xor(s, off);
        const float inv = 1.0f / s;
        #pragma unroll
        for (int r = 0; r < 8; ++r) wgt[g][(r << 6) + lane] = vals[r] * inv;
    }
    __syncthreads();

    // ---- phase D: out[g,o] = relu(sum_j sm[g][j]*y[b,g,j,o] + b_gc[g,o])
    const int o = tid & 63, gb = tid >> 6;
    #pragma unroll
    for (int gi = 0; gi < 4; ++gi) {
        const int g = (gi << 2) + gb;
        const float* yp = y + (((size_t)(bb << 4) + g) << 9) * 64 + o;
        float acc = 0.f;
        for (int j = 0; j < 512; ++j) acc = fmaf(wgt[g][j], yp[(size_t)j * 64], acc);
        const float v = fmaxf(acc + b_gc[g * 64 + o], 0.f);
        out[(size_t)bid * 1024 + g * 64 + o] = v;
    }
}

// ---------------------------------------------------------------- launch
extern "C" void kernel_launch(void* const* d_in, const int* in_sizes, int n_in,
                              void* d_out, int out_size, void* d_ws, size_t ws_size,
                              hipStream_t stream)
{
    (void)in_sizes; (void)n_in; (void)out_size; (void)ws_size;
    const float* x     = (const float*)d_in[0];
    const float* boxes = (const float*)d_in[1];
    const float* W_geo = (const float*)d_in[2];
    const float* b_geo = (const float*)d_in[3];
    const float* W_bgc = (const float*)d_in[4];
    const float* b_bgc = (const float*)d_in[5];
    const float* W_q   = (const float*)d_in[6];
    const float* b_q   = (const float*)d_in[7];
    const float* W_k   = (const float*)d_in[8];
    const float* b_k   = (const float*)d_in[9];
    const float* W_gc  = (const float*)d_in[10];
    const float* b_gc  = (const float*)d_in[11];
    float* out = (float*)d_out;

    float* fws = (float*)d_ws;
    float* gcx = fws;
    float* gcy = gcx + 4096;
    float* gw  = gcy + 4096;
    float* glw = gw  + 4096;
    float* glh = glw + 4096;
    float* qws = fws + 5 * 4096;              // [4096,1024]
    float* kws = qws + 4096 * 1024;           // [4096,1024]
    float* yws = kws + 4096 * 1024;           // [8,16,512,64]

    geom_kernel<<<16, 256, 0, stream>>>(boxes, gcx, gcy, gw, glw, glh);
    gemm_nt<<<dim3(16, 64, 1), 256, 0, stream>>>(x, W_q, b_q, qws, 4096, 1024, 1024, 0);
    gemm_nt<<<dim3(16, 64, 1), 256, 0, stream>>>(x, W_k, b_k, kws, 4096, 1024, 1024, 0);
    gemm_nt<<<dim3(1, 8, 128), 256, 0, stream>>>(x, W_gc, nullptr, yws, 512, 64, 1024, 1);
    attn_kernel<<<4096, 256, 0, stream>>>(gcx, gcy, gw, glw, glh, qws, kws, yws,
                                          W_geo, b_geo, W_bgc, b_bgc, b_gc, out);
}

// Round 3
// 821.419 us; speedup vs baseline: 10.6222x; 10.6222x over previous
//
#include <hip/hip_runtime.h>
#include <math.h>

// BS=8, ROI=512, D=1024, G=16, DH=64, GEO=64, N_total=4096
// All I/O float32.

__device__ __forceinline__ float fast_tanh(float x) {
    const float ax = fabsf(x);
    const float e = __expf(-2.0f * ax);
    const float t = (1.0f - e) / (1.0f + e);
    return copysignf(t, x);
}

// ---------------------------------------------------------------- geometry
__global__ __launch_bounds__(256) void geom_kernel(
    const float* __restrict__ boxes,
    float* __restrict__ gcx, float* __restrict__ gcy,
    float* __restrict__ gw,  float* __restrict__ glw, float* __restrict__ glh)
{
    const int i = blockIdx.x * 256 + threadIdx.x;
    if (i >= 4096) return;
    const float x1 = boxes[i * 4 + 0];
    const float y1 = boxes[i * 4 + 1];
    const float x2 = boxes[i * 4 + 2];
    const float y2 = boxes[i * 4 + 3];
    const float w = x2 - x1, h = y2 - y1;
    gcx[i] = 0.5f * (x1 + x2);
    gcy[i] = 0.5f * (y1 + y2);
    gw[i]  = w;
    glw[i] = logf(w);
    glh[i] = logf(h);
}

// ------------------------------------------------- NT GEMM (Q/K projections)
// C[m,n] = sum_k A[m,k]*B[n,k] + bias[n]; A:[M,K], B:[N,K] row-major f32.
__global__ __launch_bounds__(256) void gemm_nt(
    const float* __restrict__ A, const float* __restrict__ B,
    const float* __restrict__ bias, float* __restrict__ C,
    int M, int N, int K)
{
    __shared__ float As[16][64];
    __shared__ float Bs[16][64];
    const int tid = threadIdx.x;
    const int m0 = blockIdx.y << 6;
    const int n0 = blockIdx.x << 6;
    const int tx = tid & 15, ty = tid >> 4;
    const int lr = tid >> 2;
    const int lk = (tid & 3) << 2;
    float acc[4][4] = {{0.f}};

    for (int k0 = 0; k0 < K; k0 += 16) {
        const float4 a4 = *reinterpret_cast<const float4*>(A + (size_t)(m0 + lr) * K + k0 + lk);
        const float4 b4 = *reinterpret_cast<const float4*>(B + (size_t)(n0 + lr) * K + k0 + lk);
        As[lk + 0][lr] = a4.x; As[lk + 1][lr] = a4.y;
        As[lk + 2][lr] = a4.z; As[lk + 3][lr] = a4.w;
        Bs[lk + 0][lr] = b4.x; Bs[lk + 1][lr] = b4.y;
        Bs[lk + 2][lr] = b4.z; Bs[lk + 3][lr] = b4.w;
        __syncthreads();
        #pragma unroll
        for (int kk = 0; kk < 16; ++kk) {
            float a[4], b[4];
            #pragma unroll
            for (int i = 0; i < 4; ++i) a[i] = As[kk][(ty << 2) + i];
            #pragma unroll
            for (int j = 0; j < 4; ++j) b[j] = Bs[kk][(tx << 2) + j];
            #pragma unroll
            for (int i = 0; i < 4; ++i)
                #pragma unroll
                for (int j = 0; j < 4; ++j) acc[i][j] = fmaf(a[i], b[j], acc[i][j]);
        }
        __syncthreads();
    }
    #pragma unroll
    for (int i = 0; i < 4; ++i) {
        const int row = m0 + (ty << 2) + i;
        #pragma unroll
        for (int j = 0; j < 4; ++j) {
            const int col = n0 + (tx << 2) + j;
            C[(size_t)row * N + col] = acc[i][j] + bias[col];
        }
    }
}

// ----------------------------------- y_t[b,g,o,j] = sum_d x[b,j,d]*W_gc[g,o,d]
// grid (1, 8, 128): z = b*16+g. M=512 (j rows), N=64 (o), K=1024. Transposed write.
__global__ __launch_bounds__(256) void gemm_y_t(
    const float* __restrict__ x, const float* __restrict__ W_gc,
    float* __restrict__ y_t)
{
    const int bz = blockIdx.z;
    const float* A = x + (size_t)(bz >> 4) * 512 * 1024;       // rows j
    const float* B = W_gc + (size_t)(bz & 15) * 64 * 1024;     // rows o
    float* C = y_t + (size_t)bz * 64 * 512;

    __shared__ float As[16][64];
    __shared__ float Bs[16][64];
    const int tid = threadIdx.x;
    const int m0 = blockIdx.y << 6;
    const int tx = tid & 15, ty = tid >> 4;
    const int lr = tid >> 2;
    const int lk = (tid & 3) << 2;
    float acc[4][4] = {{0.f}};

    for (int k0 = 0; k0 < 1024; k0 += 16) {
        const float4 a4 = *reinterpret_cast<const float4*>(A + (size_t)(m0 + lr) * 1024 + k0 + lk);
        const float4 b4 = *reinterpret_cast<const float4*>(B + (size_t)lr * 1024 + k0 + lk);
        As[lk + 0][lr] = a4.x; As[lk + 1][lr] = a4.y;
        As[lk + 2][lr] = a4.z; As[lk + 3][lr] = a4.w;
        Bs[lk + 0][lr] = b4.x; Bs[lk + 1][lr] = b4.y;
        Bs[lk + 2][lr] = b4.z; Bs[lk + 3][lr] = b4.w;
        __syncthreads();
        #pragma unroll
        for (int kk = 0; kk < 16; ++kk) {
            float a[4], b[4];
            #pragma unroll
            for (int i = 0; i < 4; ++i) a[i] = As[kk][(ty << 2) + i];
            #pragma unroll
            for (int j = 0; j < 4; ++j) b[j] = Bs[kk][(tx << 2) + j];
            #pragma unroll
            for (int i = 0; i < 4; ++i)
                #pragma unroll
                for (int j = 0; j < 4; ++j) acc[i][j] = fmaf(a[i], b[j], acc[i][j]);
        }
        __syncthreads();
    }
    #pragma unroll
    for (int i = 0; i < 4; ++i) {
        const int row = m0 + (ty << 2) + i;          // j
        #pragma unroll
        for (int j = 0; j < 4; ++j) {
            const int col = (tx << 2) + j;           // o
            C[(size_t)col * 512 + row] = acc[i][j];  // transposed
        }
    }
}

// -------------------------------------------- geo MLP -> S[b,g,i,j] (base term)
__global__ __launch_bounds__(256) void geo_kernel(
    const float* __restrict__ gcx, const float* __restrict__ gcy,
    const float* __restrict__ gw,  const float* __restrict__ glw,
    const float* __restrict__ glh,
    const float* __restrict__ W_geo, const float* __restrict__ b_geo,
    const float* __restrict__ W_bgc, const float* __restrict__ b_bgc,
    float* __restrict__ S)
{
    __shared__ float sWg[256];
    __shared__ float sbg[64];
    __shared__ float sWb[1024];
    __shared__ float sbb[16];
    const int tid = threadIdx.x;
    const int bid = blockIdx.x;        // b*512 + i
    const int bb = bid >> 9;
    const int ii = bid & 511;

    sWg[tid] = W_geo[tid];
    if (tid < 64) sbg[tid] = b_geo[tid];
    if (tid < 16) sbb[tid] = b_bgc[tid];
    for (int l = tid; l < 1024; l += 256) sWb[l] = W_bgc[l];
    __syncthreads();

    const float cxi = gcx[bid], cyi = gcy[bid];
    const float rwi = 1.0f / gw[bid];
    const float lwi = glw[bid], lhi = glh[bid];

    for (int j = tid; j < 512; j += 256) {
        const int jg = (bb << 9) + j;
        const float e0 = __logf(fmaxf(fabsf((cxi - gcx[jg]) * rwi), 1e-3f));
        const float e1 = __logf(fmaxf(fabsf((cyi - gcy[jg]) * rwi), 1e-3f));
        const float e2 = lwi - glw[jg];
        const float e3 = lhi - glh[jg];
        float acc[16];
        #pragma unroll
        for (int g = 0; g < 16; ++g) acc[g] = 0.f;
        #pragma unroll 4
        for (int d = 0; d < 64; ++d) {
            float hv = fmaf(e0, sWg[d * 4 + 0], fmaf(e1, sWg[d * 4 + 1],
                       fmaf(e2, sWg[d * 4 + 2], fmaf(e3, sWg[d * 4 + 3], sbg[d]))));
            hv = fast_tanh(hv);
            #pragma unroll
            for (int g = 0; g < 16; ++g) acc[g] = fmaf(sWb[g * 64 + d], hv, acc[g]);
        }
        #pragma unroll
        for (int g = 0; g < 16; ++g) {
            const float v = fmaxf(acc[g] + sbb[g], 0.f);
            S[(((size_t)(bb * 16 + g) * 512 + ii) * 512) + j] = __logf(fmaxf(v, 1e-6f));
        }
    }
}

// --------------------------- S[b,g,i,j] += 0.125 * sum_d q[b,i,gd]*k[b,j,gd]
// grid (8, 8, 128): z = b*16+g. 64x64 tile, K=64.
__global__ __launch_bounds__(256) void gemm_logits(
    const float* __restrict__ q, const float* __restrict__ k,
    float* __restrict__ S)
{
    const int z = blockIdx.z;
    const int b = z >> 4, g = z & 15;
    const int m0 = blockIdx.y << 6;     // i
    const int n0 = blockIdx.x << 6;     // j
    const float* A = q + ((size_t)b * 512 + m0) * 1024 + g * 64;
    const float* B = k + ((size_t)b * 512 + n0) * 1024 + g * 64;
    float* C = S + (size_t)z * 512 * 512;

    __shared__ float As[16][64];
    __shared__ float Bs[16][64];
    const int tid = threadIdx.x;
    const int tx = tid & 15, ty = tid >> 4;
    const int lr = tid >> 2;
    const int lk = (tid & 3) << 2;
    float acc[4][4] = {{0.f}};

    #pragma unroll
    for (int k0 = 0; k0 < 64; k0 += 16) {
        const float4 a4 = *reinterpret_cast<const float4*>(A + (size_t)lr * 1024 + k0 + lk);
        const float4 b4 = *reinterpret_cast<const float4*>(B + (size_t)lr * 1024 + k0 + lk);
        As[lk + 0][lr] = a4.x; As[lk + 1][lr] = a4.y;
        As[lk + 2][lr] = a4.z; As[lk + 3][lr] = a4.w;
        Bs[lk + 0][lr] = b4.x; Bs[lk + 1][lr] = b4.y;
        Bs[lk + 2][lr] = b4.z; Bs[lk + 3][lr] = b4.w;
        __syncthreads();
        #pragma unroll
        for (int kk = 0; kk < 16; ++kk) {
            float a[4], b[4];
            #pragma unroll
            for (int i = 0; i < 4; ++i) a[i] = As[kk][(ty << 2) + i];
            #pragma unroll
            for (int j = 0; j < 4; ++j) b[j] = Bs[kk][(tx << 2) + j];
            #pragma unroll
            for (int i = 0; i < 4; ++i)
                #pragma unroll
                for (int j = 0; j < 4; ++j) acc[i][j] = fmaf(a[i], b[j], acc[i][j]);
        }
        __syncthreads();
    }
    #pragma unroll
    for (int i = 0; i < 4; ++i) {
        const int row = m0 + (ty << 2) + i;
        #pragma unroll
        for (int j = 0; j < 4; ++j) {
            const int col = n0 + (tx << 2) + j;
            C[(size_t)row * 512 + col] += 0.125f * acc[i][j];
        }
    }
}

// ------------------------------------- softmax over j for each (b,g,i) row
__global__ __launch_bounds__(256) void softmax_kernel(float* __restrict__ S)
{
    const int lane = threadIdx.x & 63;
    const int wid = threadIdx.x >> 6;
    const size_t row = (size_t)blockIdx.x * 4 + wid;   // 65536 rows
    float* p = S + row * 512;
    float vals[8];
    float m = -3.0e38f;
    #pragma unroll
    for (int r = 0; r < 8; ++r) {
        vals[r] = p[(r << 6) + lane];
        m = fmaxf(m, vals[r]);
    }
    #pragma unroll
    for (int off = 32; off > 0; off >>= 1) m = fmaxf(m, __shfl_xor(m, off));
    float s = 0.f;
    #pragma unroll
    for (int r = 0; r < 8; ++r) { vals[r] = __expf(vals[r] - m); s += vals[r]; }
    #pragma unroll
    for (int off = 32; off > 0; off >>= 1) s += __shfl_xor(s, off);
    const float inv = 1.0f / s;
    #pragma unroll
    for (int r = 0; r < 8; ++r) p[(r << 6) + lane] = vals[r] * inv;
}

// --------- out[b,i,g*64+o] = relu(sum_j S[b,g,i,j]*y_t[b,g,o,j] + b_gc[g,o])
// grid (1, 8, 128): z = b*16+g. M=512 (i), N=64 (o), K=512 (j).
__global__ __launch_bounds__(256) void gemm_pv(
    const float* __restrict__ S, const float* __restrict__ y_t,
    const float* __restrict__ b_gc, float* __restrict__ out)
{
    const int z = blockIdx.z;
    const int b = z >> 4, g = z & 15;
    const int m0 = blockIdx.y << 6;
    const float* A = S + (size_t)z * 512 * 512 + (size_t)m0 * 512;  // rows i
    const float* B = y_t + (size_t)z * 64 * 512;                    // rows o

    __shared__ float As[16][64];
    __shared__ float Bs[16][64];
    const int tid = threadIdx.x;
    const int tx = tid & 15, ty = tid >> 4;
    const int lr = tid >> 2;
    const int lk = (tid & 3) << 2;
    float acc[4][4] = {{0.f}};

    for (int k0 = 0; k0 < 512; k0 += 16) {
        const float4 a4 = *reinterpret_cast<const float4*>(A + (size_t)lr * 512 + k0 + lk);
        const float4 b4 = *reinterpret_cast<const float4*>(B + (size_t)lr * 512 + k0 + lk);
        As[lk + 0][lr] = a4.x; As[lk + 1][lr] = a4.y;
        As[lk + 2][lr] = a4.z; As[lk + 3][lr] = a4.w;
        Bs[lk + 0][lr] = b4.x; Bs[lk + 1][lr] = b4.y;
        Bs[lk + 2][lr] = b4.z; Bs[lk + 3][lr] = b4.w;
        __syncthreads();
        #pragma unroll
        for (int kk = 0; kk < 16; ++kk) {
            float a[4], bv[4];
            #pragma unroll
            for (int i = 0; i < 4; ++i) a[i] = As[kk][(ty << 2) + i];
            #pragma unroll
            for (int j = 0; j < 4; ++j) bv[j] = Bs[kk][(tx << 2) + j];
            #pragma unroll
            for (int i = 0; i < 4; ++i)
                #pragma unroll
                for (int j = 0; j < 4; ++j) acc[i][j] = fmaf(a[i], bv[j], acc[i][j]);
        }
        __syncthreads();
    }
    #pragma unroll
    for (int i = 0; i < 4; ++i) {
        const int row = m0 + (ty << 2) + i;          // i
        #pragma unroll
        for (int j = 0; j < 4; ++j) {
            const int col = (tx << 2) + j;           // o
            const float v = fmaxf(acc[i][j] + b_gc[g * 64 + col], 0.f);
            out[((size_t)b * 512 + row) * 1024 + g * 64 + col] = v;
        }
    }
}

// ---------------------------------------------------------------- launch
extern "C" void kernel_launch(void* const* d_in, const int* in_sizes, int n_in,
                              void* d_out, int out_size, void* d_ws, size_t ws_size,
                              hipStream_t stream)
{
    (void)in_sizes; (void)n_in; (void)out_size; (void)ws_size;
    const float* x     = (const float*)d_in[0];
    const float* boxes = (const float*)d_in[1];
    const float* W_geo = (const float*)d_in[2];
    const float* b_geo = (const float*)d_in[3];
    const float* W_bgc = (const float*)d_in[4];
    const float* b_bgc = (const float*)d_in[5];
    const float* W_q   = (const float*)d_in[6];
    const float* b_q   = (const float*)d_in[7];
    const float* W_k   = (const float*)d_in[8];
    const float* b_k   = (const float*)d_in[9];
    const float* W_gc  = (const float*)d_in[10];
    const float* b_gc  = (const float*)d_in[11];
    float* out = (float*)d_out;

    float* fws = (float*)d_ws;
    float* gcx = fws;
    float* gcy = gcx + 4096;
    float* gw  = gcy + 4096;
    float* glw = gw  + 4096;
    float* glh = glw + 4096;
    float* qws = fws + 5 * 4096;              // [4096,1024]      16.8 MB
    float* kws = qws + 4096 * 1024;           // [4096,1024]      16.8 MB
    float* ytw = kws + 4096 * 1024;           // [8,16,64,512]    16.8 MB
    float* Sws = ytw + 4096 * 1024;           // [8,16,512,512]   67.1 MB

    geom_kernel<<<16, 256, 0, stream>>>(boxes, gcx, gcy, gw, glw, glh);
    gemm_nt<<<dim3(16, 64, 1), 256, 0, stream>>>(x, W_q, b_q, qws, 4096, 1024, 1024);
    gemm_nt<<<dim3(16, 64, 1), 256, 0, stream>>>(x, W_k, b_k, kws, 4096, 1024, 1024);
    gemm_y_t<<<dim3(1, 8, 128), 256, 0, stream>>>(x, W_gc, ytw);
    geo_kernel<<<4096, 256, 0, stream>>>(gcx, gcy, gw, glw, glh,
                                         W_geo, b_geo, W_bgc, b_bgc, Sws);
    gemm_logits<<<dim3(8, 8, 128), 256, 0, stream>>>(qws, kws, Sws);
    softmax_kernel<<<16384, 256, 0, stream>>>(Sws);
    gemm_pv<<<dim3(1, 8, 128), 256, 0, stream>>>(Sws, ytw, b_gc, out);
}